// Round 1
// baseline (623.003 us; speedup 1.0000x reference)
//
#include <hip/hip_runtime.h>

#define LEAKY_SLOPE 0.01f
#define LN_EPS 1e-6f

__device__ __forceinline__ float head_sel(int h, float a, float b, float c, float d) {
    float lo = (h & 1) ? b : a;
    float hi = (h & 1) ? d : c;
    return (h & 2) ? hi : lo;
}

// ---------------------------------------------------------------------------
// K1: node projection. One wave per node. Wn[n,h*16+f] = sum_i W[h,f,i]*nodes[n,i]
// Also s_s[n,h] = dot(Wn[n,h,:], a_s[h]), s_r likewise, lm_self = leaky(s_s+s_r).
// ---------------------------------------------------------------------------
__global__ __launch_bounds__(256) void node_proj_kernel(
    const float* __restrict__ nodes, const float* __restrict__ W,
    const float* __restrict__ a, float* __restrict__ Wn,
    float* __restrict__ s_s, float* __restrict__ s_r,
    float* __restrict__ lm_self, int N)
{
    __shared__ float Wt[64][65];   // transposed, +1 pad: Wt[i][o] = W[o*64+i]
    int t = threadIdx.x;
    #pragma unroll
    for (int k = 0; k < 16; k++) {
        int flat = k * 256 + t;
        Wt[flat & 63][flat >> 6] = W[flat];
    }
    __syncthreads();
    int lane = t & 63;
    int n = blockIdx.x * 4 + (t >> 6);
    if (n >= N) return;
    float nv = nodes[(size_t)n * 64 + lane];
    float acc = 0.f;
    #pragma unroll
    for (int i = 0; i < 64; i++)
        acc += Wt[i][lane] * __shfl(nv, i);
    Wn[(size_t)n * 64 + lane] = acc;
    int h = lane >> 4, f = lane & 15;
    float ps = acc * a[h * 48 + f];
    float pr = acc * a[h * 48 + 16 + f];
    #pragma unroll
    for (int off = 1; off < 16; off <<= 1) {
        ps += __shfl_xor(ps, off);
        pr += __shfl_xor(pr, off);
    }
    if (f == 0) {
        s_s[n * 4 + h] = ps;
        s_r[n * 4 + h] = pr;
        float v = ps + pr;
        lm_self[n * 4 + h] = v > 0.f ? v : LEAKY_SLOPE * v;
    }
}

// ---------------------------------------------------------------------------
// K2: histogram of receivers
// ---------------------------------------------------------------------------
__global__ __launch_bounds__(256) void count_kernel(
    const int* __restrict__ receivers, int* __restrict__ counts, int E)
{
    int e = blockIdx.x * 256 + threadIdx.x;
    if (e < E) atomicAdd(&counts[receivers[e]], 1);
}

// ---------------------------------------------------------------------------
// K3: single-block chunked exclusive scan of counts -> row_ptr, cursor
// ---------------------------------------------------------------------------
__global__ __launch_bounds__(1024) void scan_kernel(
    const int* __restrict__ counts, int* __restrict__ row_ptr,
    int* __restrict__ cursor, int N)
{
    __shared__ int part[1024];
    int t = threadIdx.x;
    int chunk = (N + 1023) / 1024;
    int beg = t * chunk;
    int end = min(beg + chunk, N);
    int sum = 0;
    for (int i = beg; i < end; i++) sum += counts[i];
    part[t] = sum;
    __syncthreads();
    for (int off = 1; off < 1024; off <<= 1) {
        int v = part[t];
        int u = (t >= off) ? part[t - off] : 0;
        __syncthreads();
        part[t] = v + u;
        __syncthreads();
    }
    int run = (t == 0) ? 0 : part[t - 1];
    for (int i = beg; i < end; i++) {
        int c = counts[i];
        row_ptr[i] = run;
        cursor[i] = run;
        run += c;
    }
    if (t == 1023) row_ptr[N] = part[1023];
}

// ---------------------------------------------------------------------------
// K4: per-edge logits + scatter into CSR slots (payload: sender, lm float4)
// ---------------------------------------------------------------------------
__global__ __launch_bounds__(256) void edge_kernel(
    const float* __restrict__ edges, const int* __restrict__ receivers,
    const int* __restrict__ senders, const float* __restrict__ W_edge,
    const float* __restrict__ a, const float* __restrict__ s_s,
    const float* __restrict__ s_r, int* __restrict__ cursor,
    int* __restrict__ sorted_sender, float4* __restrict__ sorted_lm, int E)
{
    __shared__ float be[4][16];   // be[h][i] = sum_f W_edge[h,f,i]*a_e[h,f]
    int t = threadIdx.x;
    if (t < 64) {
        int h = t >> 4, i = t & 15;
        float s = 0.f;
        #pragma unroll
        for (int f = 0; f < 16; f++)
            s += W_edge[(h * 16 + f) * 16 + i] * a[h * 48 + 32 + f];
        be[h][i] = s;
    }
    __syncthreads();
    int e = blockIdx.x * 256 + t;
    if (e >= E) return;
    int r = receivers[e], s = senders[e];
    const float4* ef = (const float4*)(edges + (size_t)e * 16);
    float4 e0 = ef[0], e1 = ef[1], e2 = ef[2], e3 = ef[3];
    float4 ssv = ((const float4*)s_s)[s];
    float4 srv = ((const float4*)s_r)[r];
    float ev[16] = {e0.x, e0.y, e0.z, e0.w, e1.x, e1.y, e1.z, e1.w,
                    e2.x, e2.y, e2.z, e2.w, e3.x, e3.y, e3.z, e3.w};
    float ssa[4] = {ssv.x, ssv.y, ssv.z, ssv.w};
    float sra[4] = {srv.x, srv.y, srv.z, srv.w};
    float lm[4];
    #pragma unroll
    for (int hh = 0; hh < 4; hh++) {
        float se = 0.f;
        #pragma unroll
        for (int i = 0; i < 16; i++) se += be[hh][i] * ev[i];
        float v = ssa[hh] + sra[hh] + se;
        lm[hh] = v > 0.f ? v : LEAKY_SLOPE * v;
    }
    int pos = atomicAdd(&cursor[r], 1);
    sorted_sender[pos] = s;
    sorted_lm[pos] = make_float4(lm[0], lm[1], lm[2], lm[3]);
}

// ---------------------------------------------------------------------------
// K5: per-node softmax + aggregation + ELU + LayerNorm. One wave per node,
// lane = h*16+f owns one output feature.
// ---------------------------------------------------------------------------
__global__ __launch_bounds__(256) void node_aggr_kernel(
    const float* __restrict__ Wn, const float* __restrict__ lm_self,
    const int* __restrict__ row_ptr, const int* __restrict__ sorted_sender,
    const float4* __restrict__ sorted_lm, const float* __restrict__ ln_scale,
    const float* __restrict__ ln_bias, float* __restrict__ out, int N)
{
    int t = threadIdx.x;
    int lane = t & 63;
    int n = blockIdx.x * 4 + (t >> 6);
    if (n >= N) return;
    int beg = row_ptr[n], end = row_ptr[n + 1];
    int h = lane >> 4;

    // ---- pass A: online (max, sumexp) per head across this node's edges ----
    float m0 = -1e30f, m1 = -1e30f, m2 = -1e30f, m3 = -1e30f;
    float s0 = 0.f, s1 = 0.f, s2 = 0.f, s3 = 0.f;
    for (int j = beg + lane; j < end; j += 64) {
        float4 v = sorted_lm[j];
        float nm;
        nm = fmaxf(m0, v.x); s0 = s0 * __expf(m0 - nm) + __expf(v.x - nm); m0 = nm;
        nm = fmaxf(m1, v.y); s1 = s1 * __expf(m1 - nm) + __expf(v.y - nm); m1 = nm;
        nm = fmaxf(m2, v.z); s2 = s2 * __expf(m2 - nm) + __expf(v.z - nm); m2 = nm;
        nm = fmaxf(m3, v.w); s3 = s3 * __expf(m3 - nm) + __expf(v.w - nm); m3 = nm;
    }
    #pragma unroll
    for (int off = 1; off < 64; off <<= 1) {
        float om, os, nm;
        om = __shfl_xor(m0, off); os = __shfl_xor(s0, off);
        nm = fmaxf(m0, om); s0 = s0 * __expf(m0 - nm) + os * __expf(om - nm); m0 = nm;
        om = __shfl_xor(m1, off); os = __shfl_xor(s1, off);
        nm = fmaxf(m1, om); s1 = s1 * __expf(m1 - nm) + os * __expf(om - nm); m1 = nm;
        om = __shfl_xor(m2, off); os = __shfl_xor(s2, off);
        nm = fmaxf(m2, om); s2 = s2 * __expf(m2 - nm) + os * __expf(om - nm); m2 = nm;
        om = __shfl_xor(m3, off); os = __shfl_xor(s3, off);
        nm = fmaxf(m3, om); s3 = s3 * __expf(m3 - nm) + os * __expf(om - nm); m3 = nm;
    }
    // fold in self edge
    float4 ls = ((const float4*)lm_self)[n];
    float mf0 = fmaxf(m0, ls.x), mf1 = fmaxf(m1, ls.y);
    float mf2 = fmaxf(m2, ls.z), mf3 = fmaxf(m3, ls.w);
    float nr0 = s0 * __expf(m0 - mf0) + __expf(ls.x - mf0);
    float nr1 = s1 * __expf(m1 - mf1) + __expf(ls.y - mf1);
    float nr2 = s2 * __expf(m2 - mf2) + __expf(ls.z - mf2);
    float nr3 = s3 * __expf(m3 - mf3) + __expf(ls.w - mf3);

    float mh  = head_sel(h, mf0, mf1, mf2, mf3);
    float inv = 1.f / head_sel(h, nr0, nr1, nr2, nr3);
    float lsh = head_sel(h, ls.x, ls.y, ls.z, ls.w);

    // ---- pass B: unnormalized weighted aggregation (self first) ----
    float acc = __expf(lsh - mh) * Wn[(size_t)n * 64 + lane];
    for (int base = beg; base < end; base += 64) {
        int j = base + lane;
        int sv = 0;
        float a0 = 0.f, a1 = 0.f, a2 = 0.f, a3 = 0.f;
        if (j < end) {
            sv = sorted_sender[j];
            float4 v = sorted_lm[j];
            a0 = __expf(v.x - mf0); a1 = __expf(v.y - mf1);
            a2 = __expf(v.z - mf2); a3 = __expf(v.w - mf3);
        }
        int cnt = min(64, end - base);
        for (int k = 0; k < cnt; k++) {
            int sk = __shfl(sv, k);
            float b0 = __shfl(a0, k), b1 = __shfl(a1, k);
            float b2 = __shfl(a2, k), b3 = __shfl(a3, k);
            float av = head_sel(h, b0, b1, b2, b3);
            acc += av * Wn[(size_t)sk * 64 + lane];
        }
    }
    acc *= inv;

    // ---- ELU + LayerNorm over the 64 features (= 64 lanes) ----
    float y = acc > 0.f ? acc : expm1f(acc);
    float sum = y;
    #pragma unroll
    for (int off = 1; off < 64; off <<= 1) sum += __shfl_xor(sum, off);
    float mean = sum * 0.015625f;
    float d = y - mean;
    float vs = d * d;
    #pragma unroll
    for (int off = 1; off < 64; off <<= 1) vs += __shfl_xor(vs, off);
    float var = vs * 0.015625f;
    float o = d * rsqrtf(var + LN_EPS) * ln_scale[lane] + ln_bias[lane];
    out[(size_t)n * 64 + lane] = o;
}

// ---------------------------------------------------------------------------
extern "C" void kernel_launch(void* const* d_in, const int* in_sizes, int n_in,
                              void* d_out, int out_size, void* d_ws, size_t ws_size,
                              hipStream_t stream) {
    const float* nodes     = (const float*)d_in[0];
    const float* edges     = (const float*)d_in[1];
    const int*   receivers = (const int*)d_in[2];
    const int*   senders   = (const int*)d_in[3];
    const float* W         = (const float*)d_in[4];
    const float* W_edge    = (const float*)d_in[5];
    const float* a         = (const float*)d_in[6];
    const float* ln_scale  = (const float*)d_in[7];
    const float* ln_bias   = (const float*)d_in[8];
    float* out = (float*)d_out;

    int N = in_sizes[0] / 64;
    int E = in_sizes[2];

    char* ws = (char*)d_ws;
    size_t off = 0;
    auto alloc = [&](size_t bytes) -> void* {
        void* p = ws + off;
        off += (bytes + 15) & ~(size_t)15;
        return p;
    };
    float* Wn            = (float*)alloc((size_t)N * 64 * 4);
    float* s_s           = (float*)alloc((size_t)N * 4 * 4);
    float* s_r           = (float*)alloc((size_t)N * 4 * 4);
    float* lm_self       = (float*)alloc((size_t)N * 4 * 4);
    int*   counts        = (int*)alloc((size_t)N * 4);
    int*   row_ptr       = (int*)alloc((size_t)(N + 1) * 4);
    int*   cursor        = (int*)alloc((size_t)N * 4);
    int*   sorted_sender = (int*)alloc((size_t)E * 4);
    float4* sorted_lm    = (float4*)alloc((size_t)E * 16);
    (void)ws_size; (void)n_in; (void)out_size;

    hipMemsetAsync(counts, 0, (size_t)N * 4, stream);

    node_proj_kernel<<<(N + 3) / 4, 256, 0, stream>>>(
        nodes, W, a, Wn, s_s, s_r, lm_self, N);
    count_kernel<<<(E + 255) / 256, 256, 0, stream>>>(receivers, counts, E);
    scan_kernel<<<1, 1024, 0, stream>>>(counts, row_ptr, cursor, N);
    edge_kernel<<<(E + 255) / 256, 256, 0, stream>>>(
        edges, receivers, senders, W_edge, a, s_s, s_r,
        cursor, sorted_sender, sorted_lm, E);
    node_aggr_kernel<<<(N + 3) / 4, 256, 0, stream>>>(
        Wn, lm_self, row_ptr, sorted_sender, sorted_lm,
        ln_scale, ln_bias, out, N);
}

// Round 2
// 537.893 us; speedup vs baseline: 1.1582x; 1.1582x over previous
//
#include <hip/hip_runtime.h>
#include <hip/hip_fp16.h>

#define LEAKY_SLOPE 0.01f
#define LN_EPS 1e-6f

__device__ __forceinline__ float head_sel(int h, float a, float b, float c, float d) {
    float lo = (h & 1) ? b : a;
    float hi = (h & 1) ? d : c;
    return (h & 2) ? hi : lo;
}

// ---------------------------------------------------------------------------
// K1: node projection. One wave per node. Wn[n,h*16+f] = sum_i W[h,f,i]*nodes[n,i]
// Also s_s[n,h] = dot(Wn[n,h,:], a_s[h]), s_r likewise, lm_self = leaky(s_s+s_r).
// ---------------------------------------------------------------------------
__global__ __launch_bounds__(256) void node_proj_kernel(
    const float* __restrict__ nodes, const float* __restrict__ W,
    const float* __restrict__ a, float* __restrict__ Wn,
    float* __restrict__ s_s, float* __restrict__ s_r,
    float* __restrict__ lm_self, int N)
{
    __shared__ float Wt[64][65];   // transposed, +1 pad: Wt[i][o] = W[o*64+i]
    int t = threadIdx.x;
    #pragma unroll
    for (int k = 0; k < 16; k++) {
        int flat = k * 256 + t;
        Wt[flat & 63][flat >> 6] = W[flat];
    }
    __syncthreads();
    int lane = t & 63;
    int n = blockIdx.x * 4 + (t >> 6);
    if (n >= N) return;
    float nv = nodes[(size_t)n * 64 + lane];
    float acc = 0.f;
    #pragma unroll
    for (int i = 0; i < 64; i++)
        acc += Wt[i][lane] * __shfl(nv, i);
    Wn[(size_t)n * 64 + lane] = acc;
    int h = lane >> 4, f = lane & 15;
    float ps = acc * a[h * 48 + f];
    float pr = acc * a[h * 48 + 16 + f];
    #pragma unroll
    for (int off = 1; off < 16; off <<= 1) {
        ps += __shfl_xor(ps, off);
        pr += __shfl_xor(pr, off);
    }
    if (f == 0) {
        s_s[n * 4 + h] = ps;
        s_r[n * 4 + h] = pr;
        float v = ps + pr;
        lm_self[n * 4 + h] = v > 0.f ? v : LEAKY_SLOPE * v;
    }
}

// ---------------------------------------------------------------------------
// K2: histogram of receivers (int4 vectorized reads)
// ---------------------------------------------------------------------------
__global__ __launch_bounds__(256) void count_kernel(
    const int* __restrict__ receivers, int* __restrict__ counts, int E)
{
    int i = blockIdx.x * 256 + threadIdx.x;
    int base = i * 4;
    if (base + 3 < E) {
        int4 v = ((const int4*)receivers)[i];
        atomicAdd(&counts[v.x], 1);
        atomicAdd(&counts[v.y], 1);
        atomicAdd(&counts[v.z], 1);
        atomicAdd(&counts[v.w], 1);
    } else {
        for (int e = base; e < E; e++) atomicAdd(&counts[receivers[e]], 1);
    }
}

// ---------------------------------------------------------------------------
// K3: single-block chunked exclusive scan of counts -> row_ptr, cursor
// ---------------------------------------------------------------------------
__global__ __launch_bounds__(1024) void scan_kernel(
    const int* __restrict__ counts, int* __restrict__ row_ptr,
    int* __restrict__ cursor, int N)
{
    __shared__ int part[1024];
    int t = threadIdx.x;
    int chunk = (N + 1023) / 1024;
    int beg = t * chunk;
    int end = min(beg + chunk, N);
    int sum = 0;
    for (int i = beg; i < end; i++) sum += counts[i];
    part[t] = sum;
    __syncthreads();
    for (int off = 1; off < 1024; off <<= 1) {
        int v = part[t];
        int u = (t >= off) ? part[t - off] : 0;
        __syncthreads();
        part[t] = v + u;
        __syncthreads();
    }
    int run = (t == 0) ? 0 : part[t - 1];
    for (int i = beg; i < end; i++) {
        int c = counts[i];
        row_ptr[i] = run;
        cursor[i] = run;
        run += c;
    }
    if (t == 1023) row_ptr[N] = part[1023];
}

// ---------------------------------------------------------------------------
// K4: per-edge logits + scatter into CSR slots.
// Payload 16B: {lm0 f32, lm1 f32, lm2 f32, (lm3 fp16 | sender u16 << 16)}
// ---------------------------------------------------------------------------
__global__ __launch_bounds__(256) void edge_kernel(
    const float* __restrict__ edges, const int* __restrict__ receivers,
    const int* __restrict__ senders, const float* __restrict__ W_edge,
    const float* __restrict__ a, const float* __restrict__ s_s,
    const float* __restrict__ s_r, int* __restrict__ cursor,
    int4* __restrict__ sorted, int E)
{
    __shared__ float be[4][16];   // be[h][i] = sum_f W_edge[h,f,i]*a_e[h,f]
    int t = threadIdx.x;
    if (t < 64) {
        int h = t >> 4, i = t & 15;
        float s = 0.f;
        #pragma unroll
        for (int f = 0; f < 16; f++)
            s += W_edge[(h * 16 + f) * 16 + i] * a[h * 48 + 32 + f];
        be[h][i] = s;
    }
    __syncthreads();
    int e = blockIdx.x * 256 + t;
    if (e >= E) return;
    int r = receivers[e], s = senders[e];
    const float4* ef = (const float4*)(edges + (size_t)e * 16);
    float4 e0 = ef[0], e1 = ef[1], e2 = ef[2], e3 = ef[3];
    float4 ssv = ((const float4*)s_s)[s];
    float4 srv = ((const float4*)s_r)[r];
    float ev[16] = {e0.x, e0.y, e0.z, e0.w, e1.x, e1.y, e1.z, e1.w,
                    e2.x, e2.y, e2.z, e2.w, e3.x, e3.y, e3.z, e3.w};
    float ssa[4] = {ssv.x, ssv.y, ssv.z, ssv.w};
    float sra[4] = {srv.x, srv.y, srv.z, srv.w};
    float lm[4];
    #pragma unroll
    for (int hh = 0; hh < 4; hh++) {
        float se = 0.f;
        #pragma unroll
        for (int i = 0; i < 16; i++) se += be[hh][i] * ev[i];
        float v = ssa[hh] + sra[hh] + se;
        lm[hh] = v > 0.f ? v : LEAKY_SLOPE * v;
    }
    int pos = atomicAdd(&cursor[r], 1);
    unsigned pack = (unsigned)__half_as_ushort(__float2half(lm[3])) |
                    ((unsigned)s << 16);
    sorted[pos] = make_int4(__float_as_int(lm[0]), __float_as_int(lm[1]),
                            __float_as_int(lm[2]), (int)pack);
}

// ---------------------------------------------------------------------------
// K5: single-pass per-node softmax (no max-shift) + aggregation + ELU + LN.
// One wave per node, lane = h*16+f owns one output feature. LDS-staged chunks,
// no barriers (wave-private LDS regions).
// ---------------------------------------------------------------------------
__global__ __launch_bounds__(256) void node_aggr_kernel(
    const float* __restrict__ Wn, const float* __restrict__ lm_self,
    const int* __restrict__ row_ptr, const int4* __restrict__ sorted,
    const float* __restrict__ ln_scale, const float* __restrict__ ln_bias,
    float* __restrict__ out, int N)
{
    __shared__ float lds_w[4][64][4];
    __shared__ int   lds_s[4][64];
    int t = threadIdx.x;
    int lane = t & 63;
    int wv = t >> 6;
    int n = blockIdx.x * 4 + wv;
    if (n >= N) return;
    int beg = row_ptr[n], end = row_ptr[n + 1];
    int h = lane >> 4;

    float acc = 0.f, acc2 = 0.f;
    float p0 = 0.f, p1 = 0.f, p2 = 0.f, p3 = 0.f;  // partial softmax denoms

    for (int base = beg; base < end; base += 64) {
        int j = base + lane;
        float w0 = 0.f, w1 = 0.f, w2 = 0.f, w3 = 0.f;
        int sv = 0;
        if (j < end) {
            int4 pl = sorted[j];
            w0 = __expf(__int_as_float(pl.x));
            w1 = __expf(__int_as_float(pl.y));
            w2 = __expf(__int_as_float(pl.z));
            unsigned u = (unsigned)pl.w;
            w3 = __expf(__half2float(__ushort_as_half((unsigned short)(u & 0xFFFFu))));
            sv = (int)(u >> 16);
        }
        p0 += w0; p1 += w1; p2 += w2; p3 += w3;
        lds_s[wv][lane] = sv;
        *(float4*)&lds_w[wv][lane][0] = make_float4(w0, w1, w2, w3);
        int cnt = min(64, end - base);
        int k = 0;
        for (; k + 1 < cnt; k += 2) {
            int   sk0 = lds_s[wv][k];
            int   sk1 = lds_s[wv][k + 1];
            float a0  = lds_w[wv][k][h];
            float a1  = lds_w[wv][k + 1][h];
            float v0 = Wn[(size_t)sk0 * 64 + lane];
            float v1 = Wn[(size_t)sk1 * 64 + lane];
            acc  += a0 * v0;
            acc2 += a1 * v1;
        }
        if (k < cnt)
            acc += lds_w[wv][k][h] * Wn[(size_t)lds_s[wv][k] * 64 + lane];
    }
    acc += acc2;

    // reduce softmax denominators across the wave
    #pragma unroll
    for (int off = 1; off < 64; off <<= 1) {
        p0 += __shfl_xor(p0, off);
        p1 += __shfl_xor(p1, off);
        p2 += __shfl_xor(p2, off);
        p3 += __shfl_xor(p3, off);
    }
    // self edge
    float4 ls = ((const float4*)lm_self)[n];
    float ws0 = __expf(ls.x), ws1 = __expf(ls.y);
    float ws2 = __expf(ls.z), ws3 = __expf(ls.w);
    float tot   = head_sel(h, p0 + ws0, p1 + ws1, p2 + ws2, p3 + ws3);
    float wself = head_sel(h, ws0, ws1, ws2, ws3);
    acc = (acc + wself * Wn[(size_t)n * 64 + lane]) / tot;

    // ---- ELU + LayerNorm over the 64 features (= 64 lanes) ----
    float y = acc > 0.f ? acc : expm1f(acc);
    float sum = y;
    #pragma unroll
    for (int off = 1; off < 64; off <<= 1) sum += __shfl_xor(sum, off);
    float mean = sum * 0.015625f;
    float d = y - mean;
    float vs = d * d;
    #pragma unroll
    for (int off = 1; off < 64; off <<= 1) vs += __shfl_xor(vs, off);
    float var = vs * 0.015625f;
    float o = d * rsqrtf(var + LN_EPS) * ln_scale[lane] + ln_bias[lane];
    out[(size_t)n * 64 + lane] = o;
}

// ---------------------------------------------------------------------------
extern "C" void kernel_launch(void* const* d_in, const int* in_sizes, int n_in,
                              void* d_out, int out_size, void* d_ws, size_t ws_size,
                              hipStream_t stream) {
    const float* nodes     = (const float*)d_in[0];
    const float* edges     = (const float*)d_in[1];
    const int*   receivers = (const int*)d_in[2];
    const int*   senders   = (const int*)d_in[3];
    const float* W         = (const float*)d_in[4];
    const float* W_edge    = (const float*)d_in[5];
    const float* a         = (const float*)d_in[6];
    const float* ln_scale  = (const float*)d_in[7];
    const float* ln_bias   = (const float*)d_in[8];
    float* out = (float*)d_out;

    int N = in_sizes[0] / 64;
    int E = in_sizes[2];

    char* ws = (char*)d_ws;
    size_t off = 0;
    auto alloc = [&](size_t bytes) -> void* {
        void* p = ws + off;
        off += (bytes + 15) & ~(size_t)15;
        return p;
    };
    float* Wn      = (float*)alloc((size_t)N * 64 * 4);
    float* s_s     = (float*)alloc((size_t)N * 4 * 4);
    float* s_r     = (float*)alloc((size_t)N * 4 * 4);
    float* lm_self = (float*)alloc((size_t)N * 4 * 4);
    int*   counts  = (int*)alloc((size_t)N * 4);
    int*   row_ptr = (int*)alloc((size_t)(N + 1) * 4);
    int*   cursor  = (int*)alloc((size_t)N * 4);
    int4*  sorted  = (int4*)alloc((size_t)E * 16);
    (void)ws_size; (void)n_in; (void)out_size;

    hipMemsetAsync(counts, 0, (size_t)N * 4, stream);

    node_proj_kernel<<<(N + 3) / 4, 256, 0, stream>>>(
        nodes, W, a, Wn, s_s, s_r, lm_self, N);
    count_kernel<<<(E / 4 + 255) / 256, 256, 0, stream>>>(receivers, counts, E);
    scan_kernel<<<1, 1024, 0, stream>>>(counts, row_ptr, cursor, N);
    edge_kernel<<<(E + 255) / 256, 256, 0, stream>>>(
        edges, receivers, senders, W_edge, a, s_s, s_r,
        cursor, sorted, E);
    node_aggr_kernel<<<(N + 3) / 4, 256, 0, stream>>>(
        Wn, lm_self, row_ptr, sorted, ln_scale, ln_bias, out, N);
}

// Round 3
// 440.314 us; speedup vs baseline: 1.4149x; 1.2216x over previous
//
#include <hip/hip_runtime.h>
#include <hip/hip_fp16.h>

#define LEAKY_SLOPE 0.01f
#define LN_EPS 1e-6f

__device__ __forceinline__ float head_sel(int h, float a, float b, float c, float d) {
    float lo = (h & 1) ? b : a;
    float hi = (h & 1) ? d : c;
    return (h & 2) ? hi : lo;
}

// ---------------------------------------------------------------------------
// K1: node projection. One wave per node. Wn[n,h*16+f] = sum_i W[h,f,i]*nodes[n,i]
// Also s_s[n,h] = dot(Wn[n,h,:], a_s[h]), s_r likewise, lm_self = leaky(s_s+s_r).
// ---------------------------------------------------------------------------
__global__ __launch_bounds__(256) void node_proj_kernel(
    const float* __restrict__ nodes, const float* __restrict__ W,
    const float* __restrict__ a, float* __restrict__ Wn,
    float* __restrict__ s_s, float* __restrict__ s_r,
    float* __restrict__ lm_self, int N)
{
    __shared__ float Wt[64][65];   // transposed, +1 pad: Wt[i][o] = W[o*64+i]
    int t = threadIdx.x;
    #pragma unroll
    for (int k = 0; k < 16; k++) {
        int flat = k * 256 + t;
        Wt[flat & 63][flat >> 6] = W[flat];
    }
    __syncthreads();
    int lane = t & 63;
    int n = blockIdx.x * 4 + (t >> 6);
    if (n >= N) return;
    float nv = nodes[(size_t)n * 64 + lane];
    float acc = 0.f;
    #pragma unroll
    for (int i = 0; i < 64; i++)
        acc += Wt[i][lane] * __shfl(nv, i);
    Wn[(size_t)n * 64 + lane] = acc;
    int h = lane >> 4, f = lane & 15;
    float ps = acc * a[h * 48 + f];
    float pr = acc * a[h * 48 + 16 + f];
    #pragma unroll
    for (int off = 1; off < 16; off <<= 1) {
        ps += __shfl_xor(ps, off);
        pr += __shfl_xor(pr, off);
    }
    if (f == 0) {
        s_s[n * 4 + h] = ps;
        s_r[n * 4 + h] = pr;
        float v = ps + pr;
        lm_self[n * 4 + h] = v > 0.f ? v : LEAKY_SLOPE * v;
    }
}

// ---------------------------------------------------------------------------
// K2: histogram of receivers (int4 vectorized reads)
// ---------------------------------------------------------------------------
__global__ __launch_bounds__(256) void count_kernel(
    const int* __restrict__ receivers, int* __restrict__ counts, int E)
{
    int i = blockIdx.x * 256 + threadIdx.x;
    int base = i * 4;
    if (base + 3 < E) {
        int4 v = ((const int4*)receivers)[i];
        atomicAdd(&counts[v.x], 1);
        atomicAdd(&counts[v.y], 1);
        atomicAdd(&counts[v.z], 1);
        atomicAdd(&counts[v.w], 1);
    } else {
        for (int e = base; e < E; e++) atomicAdd(&counts[receivers[e]], 1);
    }
}

// ---------------------------------------------------------------------------
// K3a: per-block partial sums of counts (256 counts per block)
// ---------------------------------------------------------------------------
__global__ __launch_bounds__(256) void partial_sum_kernel(
    const int* __restrict__ counts, int* __restrict__ partials, int N)
{
    __shared__ int sh[4];
    int i = blockIdx.x * 256 + threadIdx.x;
    int v = (i < N) ? counts[i] : 0;
    #pragma unroll
    for (int off = 1; off < 64; off <<= 1) v += __shfl_xor(v, off);
    int lane = threadIdx.x & 63, wv = threadIdx.x >> 6;
    if (lane == 0) sh[wv] = v;
    __syncthreads();
    if (threadIdx.x == 0) partials[blockIdx.x] = sh[0] + sh[1] + sh[2] + sh[3];
}

// ---------------------------------------------------------------------------
// K3b: single tiny block: exclusive scan of the partials; row_ptr[N] = E.
// ---------------------------------------------------------------------------
__global__ __launch_bounds__(256) void scan_partials_kernel(
    int* __restrict__ partials, int B, int* __restrict__ row_ptr, int N, int E)
{
    __shared__ int sh[256];
    __shared__ int carry;
    int t = threadIdx.x;
    if (t == 0) carry = 0;
    __syncthreads();
    for (int base = 0; base < B; base += 256) {
        int idx = base + t;
        int v = (idx < B) ? partials[idx] : 0;
        sh[t] = v;
        __syncthreads();
        for (int off = 1; off < 256; off <<= 1) {
            int u = (t >= off) ? sh[t - off] : 0;
            __syncthreads();
            sh[t] += u;
            __syncthreads();
        }
        int incl = sh[t];
        int c = carry;
        if (idx < B) partials[idx] = c + incl - v;   // exclusive
        __syncthreads();
        if (t == 255) carry = c + incl;
        __syncthreads();
    }
    if (t == 0) row_ptr[N] = E;
}

// ---------------------------------------------------------------------------
// K3c: per-block exclusive scan of counts + block offset -> row_ptr, cursor
// ---------------------------------------------------------------------------
__global__ __launch_bounds__(256) void scan_apply_kernel(
    const int* __restrict__ counts, const int* __restrict__ partials,
    int* __restrict__ row_ptr, int* __restrict__ cursor, int N)
{
    __shared__ int sh[256];
    int t = threadIdx.x;
    int i = blockIdx.x * 256 + t;
    int v = (i < N) ? counts[i] : 0;
    sh[t] = v;
    __syncthreads();
    for (int off = 1; off < 256; off <<= 1) {
        int u = (t >= off) ? sh[t - off] : 0;
        __syncthreads();
        sh[t] += u;
        __syncthreads();
    }
    int excl = sh[t] - v + partials[blockIdx.x];
    if (i < N) {
        row_ptr[i] = excl;
        cursor[i] = excl;
    }
}

// ---------------------------------------------------------------------------
// K4: per-edge logits + scatter into CSR slots.
// Payload 16B: {lm0 f32, lm1 f32, lm2 f32, (lm3 fp16 | sender u16 << 16)}
// ---------------------------------------------------------------------------
__global__ __launch_bounds__(256) void edge_kernel(
    const float* __restrict__ edges, const int* __restrict__ receivers,
    const int* __restrict__ senders, const float* __restrict__ W_edge,
    const float* __restrict__ a, const float* __restrict__ s_s,
    const float* __restrict__ s_r, int* __restrict__ cursor,
    int4* __restrict__ sorted, int E)
{
    __shared__ float be[4][16];   // be[h][i] = sum_f W_edge[h,f,i]*a_e[h,f]
    int t = threadIdx.x;
    if (t < 64) {
        int h = t >> 4, i = t & 15;
        float s = 0.f;
        #pragma unroll
        for (int f = 0; f < 16; f++)
            s += W_edge[(h * 16 + f) * 16 + i] * a[h * 48 + 32 + f];
        be[h][i] = s;
    }
    __syncthreads();
    int e = blockIdx.x * 256 + t;
    if (e >= E) return;
    int r = receivers[e], s = senders[e];
    const float4* ef = (const float4*)(edges + (size_t)e * 16);
    float4 e0 = ef[0], e1 = ef[1], e2 = ef[2], e3 = ef[3];
    float4 ssv = ((const float4*)s_s)[s];
    float4 srv = ((const float4*)s_r)[r];
    float ev[16] = {e0.x, e0.y, e0.z, e0.w, e1.x, e1.y, e1.z, e1.w,
                    e2.x, e2.y, e2.z, e2.w, e3.x, e3.y, e3.z, e3.w};
    float ssa[4] = {ssv.x, ssv.y, ssv.z, ssv.w};
    float sra[4] = {srv.x, srv.y, srv.z, srv.w};
    float lm[4];
    #pragma unroll
    for (int hh = 0; hh < 4; hh++) {
        float se = 0.f;
        #pragma unroll
        for (int i = 0; i < 16; i++) se += be[hh][i] * ev[i];
        float v = ssa[hh] + sra[hh] + se;
        lm[hh] = v > 0.f ? v : LEAKY_SLOPE * v;
    }
    int pos = atomicAdd(&cursor[r], 1);
    unsigned pack = (unsigned)__half_as_ushort(__float2half(lm[3])) |
                    ((unsigned)s << 16);
    sorted[pos] = make_int4(__float_as_int(lm[0]), __float_as_int(lm[1]),
                            __float_as_int(lm[2]), (int)pack);
}

// ---------------------------------------------------------------------------
// K5: single-pass per-node softmax (no max-shift) + aggregation + ELU + LN.
// One wave per node, lane = h*16+f owns one output feature. LDS-staged chunks,
// no barriers (wave-private LDS regions).
// ---------------------------------------------------------------------------
__global__ __launch_bounds__(256) void node_aggr_kernel(
    const float* __restrict__ Wn, const float* __restrict__ lm_self,
    const int* __restrict__ row_ptr, const int4* __restrict__ sorted,
    const float* __restrict__ ln_scale, const float* __restrict__ ln_bias,
    float* __restrict__ out, int N)
{
    __shared__ float lds_w[4][64][4];
    __shared__ int   lds_s[4][64];
    int t = threadIdx.x;
    int lane = t & 63;
    int wv = t >> 6;
    int n = blockIdx.x * 4 + wv;
    if (n >= N) return;
    int beg = row_ptr[n], end = row_ptr[n + 1];
    int h = lane >> 4;

    float acc = 0.f, acc2 = 0.f;
    float p0 = 0.f, p1 = 0.f, p2 = 0.f, p3 = 0.f;  // partial softmax denoms

    for (int base = beg; base < end; base += 64) {
        int j = base + lane;
        float w0 = 0.f, w1 = 0.f, w2 = 0.f, w3 = 0.f;
        int sv = 0;
        if (j < end) {
            int4 pl = sorted[j];
            w0 = __expf(__int_as_float(pl.x));
            w1 = __expf(__int_as_float(pl.y));
            w2 = __expf(__int_as_float(pl.z));
            unsigned u = (unsigned)pl.w;
            w3 = __expf(__half2float(__ushort_as_half((unsigned short)(u & 0xFFFFu))));
            sv = (int)(u >> 16);
        }
        p0 += w0; p1 += w1; p2 += w2; p3 += w3;
        lds_s[wv][lane] = sv;
        *(float4*)&lds_w[wv][lane][0] = make_float4(w0, w1, w2, w3);
        int cnt = min(64, end - base);
        int k = 0;
        for (; k + 1 < cnt; k += 2) {
            int   sk0 = lds_s[wv][k];
            int   sk1 = lds_s[wv][k + 1];
            float a0  = lds_w[wv][k][h];
            float a1  = lds_w[wv][k + 1][h];
            float v0 = Wn[(size_t)sk0 * 64 + lane];
            float v1 = Wn[(size_t)sk1 * 64 + lane];
            acc  += a0 * v0;
            acc2 += a1 * v1;
        }
        if (k < cnt)
            acc += lds_w[wv][k][h] * Wn[(size_t)lds_s[wv][k] * 64 + lane];
    }
    acc += acc2;

    // reduce softmax denominators across the wave
    #pragma unroll
    for (int off = 1; off < 64; off <<= 1) {
        p0 += __shfl_xor(p0, off);
        p1 += __shfl_xor(p1, off);
        p2 += __shfl_xor(p2, off);
        p3 += __shfl_xor(p3, off);
    }
    // self edge
    float4 ls = ((const float4*)lm_self)[n];
    float ws0 = __expf(ls.x), ws1 = __expf(ls.y);
    float ws2 = __expf(ls.z), ws3 = __expf(ls.w);
    float tot   = head_sel(h, p0 + ws0, p1 + ws1, p2 + ws2, p3 + ws3);
    float wself = head_sel(h, ws0, ws1, ws2, ws3);
    acc = (acc + wself * Wn[(size_t)n * 64 + lane]) / tot;

    // ---- ELU + LayerNorm over the 64 features (= 64 lanes) ----
    float y = acc > 0.f ? acc : expm1f(acc);
    float sum = y;
    #pragma unroll
    for (int off = 1; off < 64; off <<= 1) sum += __shfl_xor(sum, off);
    float mean = sum * 0.015625f;
    float d = y - mean;
    float vs = d * d;
    #pragma unroll
    for (int off = 1; off < 64; off <<= 1) vs += __shfl_xor(vs, off);
    float var = vs * 0.015625f;
    float o = d * rsqrtf(var + LN_EPS) * ln_scale[lane] + ln_bias[lane];
    out[(size_t)n * 64 + lane] = o;
}

// ---------------------------------------------------------------------------
extern "C" void kernel_launch(void* const* d_in, const int* in_sizes, int n_in,
                              void* d_out, int out_size, void* d_ws, size_t ws_size,
                              hipStream_t stream) {
    const float* nodes     = (const float*)d_in[0];
    const float* edges     = (const float*)d_in[1];
    const int*   receivers = (const int*)d_in[2];
    const int*   senders   = (const int*)d_in[3];
    const float* W         = (const float*)d_in[4];
    const float* W_edge    = (const float*)d_in[5];
    const float* a         = (const float*)d_in[6];
    const float* ln_scale  = (const float*)d_in[7];
    const float* ln_bias   = (const float*)d_in[8];
    float* out = (float*)d_out;

    int N = in_sizes[0] / 64;
    int E = in_sizes[2];
    int B = (N + 255) / 256;   // scan blocks

    char* ws = (char*)d_ws;
    size_t off = 0;
    auto alloc = [&](size_t bytes) -> void* {
        void* p = ws + off;
        off += (bytes + 15) & ~(size_t)15;
        return p;
    };
    float* Wn       = (float*)alloc((size_t)N * 64 * 4);
    float* s_s      = (float*)alloc((size_t)N * 4 * 4);
    float* s_r      = (float*)alloc((size_t)N * 4 * 4);
    float* lm_self  = (float*)alloc((size_t)N * 4 * 4);
    int*   counts   = (int*)alloc((size_t)N * 4);
    int*   row_ptr  = (int*)alloc((size_t)(N + 1) * 4);
    int*   cursor   = (int*)alloc((size_t)N * 4);
    int*   partials = (int*)alloc((size_t)B * 4);
    int4*  sorted   = (int4*)alloc((size_t)E * 16);
    (void)ws_size; (void)n_in; (void)out_size;

    hipMemsetAsync(counts, 0, (size_t)N * 4, stream);

    node_proj_kernel<<<(N + 3) / 4, 256, 0, stream>>>(
        nodes, W, a, Wn, s_s, s_r, lm_self, N);
    count_kernel<<<(E / 4 + 255) / 256, 256, 0, stream>>>(receivers, counts, E);
    partial_sum_kernel<<<B, 256, 0, stream>>>(counts, partials, N);
    scan_partials_kernel<<<1, 256, 0, stream>>>(partials, B, row_ptr, N, E);
    scan_apply_kernel<<<B, 256, 0, stream>>>(counts, partials, row_ptr, cursor, N);
    edge_kernel<<<(E + 255) / 256, 256, 0, stream>>>(
        edges, receivers, senders, W_edge, a, s_s, s_r,
        cursor, sorted, E);
    node_aggr_kernel<<<(N + 3) / 4, 256, 0, stream>>>(
        Wn, lm_self, row_ptr, sorted, ln_scale, ln_bias, out, N);
}